// Round 1
// baseline (651.580 us; speedup 1.0000x reference)
//
#include <hip/hip_runtime.h>

#define DIM 256
#define HIST 200
#define MPAD 208          // 13 m-tiles of 16
#define BATCH 2048
#define HSTRIDE 264       // hist row stride in bf16 elems (+8 pad -> 16B bank shift)
#define EPSF 1e-12f

typedef __bf16 bf16x8 __attribute__((ext_vector_type(8)));
typedef float f32x4 __attribute__((ext_vector_type(4)));

__device__ __forceinline__ unsigned short f2bf(float f) {
    union { float f; unsigned u; } v; v.f = f;
    unsigned r = (v.u + 0x7fffu + ((v.u >> 16) & 1u)) >> 16;
    return (unsigned short)r;
}
__device__ __forceinline__ float bf2f(unsigned short u) {
    union { unsigned u; float f; } v; v.u = ((unsigned)u) << 16;
    return v.f;
}

// ---------- prep 1: W1t[n][k] = bf16(W1[k][n]) ----------
__global__ __launch_bounds__(256) void k_w1t(const float* __restrict__ W1,
                                             unsigned short* __restrict__ W1t) {
    __shared__ float tile[64][65];
    const int bi = blockIdx.x >> 2;   // k-block
    const int bj = blockIdx.x & 3;    // n-block
    const int tid = threadIdx.x;
#pragma unroll
    for (int it = 0; it < 16; ++it) {
        int idx = tid + it * 256;
        int r = idx >> 6, c = idx & 63;
        tile[r][c] = W1[(bi * 64 + r) * DIM + bj * 64 + c];
    }
    __syncthreads();
#pragma unroll
    for (int it = 0; it < 16; ++it) {
        int idx = tid + it * 256;
        int c = idx >> 6, r = idx & 63;
        W1t[(bj * 64 + c) * DIM + bi * 64 + r] = f2bf(tile[r][c]);
    }
}

// ---------- prep 2: C = P @ W2 + bias  (fp32, [HIST][DIM]) ----------
__global__ __launch_bounds__(256) void k_C(const float* __restrict__ P,
                                           const float* __restrict__ W2,
                                           const float* __restrict__ bias,
                                           float* __restrict__ C) {
    __shared__ float Prow[DIM];
    const int h = blockIdx.x, e = threadIdx.x;
    Prow[e] = P[h * DIM + e];
    __syncthreads();
    float acc = bias[h * DIM + e];
#pragma unroll 8
    for (int d = 0; d < DIM; ++d) acc += Prow[d] * W2[d * DIM + e];
    C[h * DIM + e] = acc;
}

// ---------- main: one block per batch element ----------
__global__ __launch_bounds__(256, 1) void k_main(
    const int* __restrict__ batch_u, const int* __restrict__ batch_v,
    const int* __restrict__ batch_history,
    const float* __restrict__ user_emb, const float* __restrict__ venue_emb,
    const float* __restrict__ Cmat, const unsigned short* __restrict__ W1t,
    const float* __restrict__ a_ptr, float* __restrict__ out) {

    __shared__ unsigned short histS[MPAD * HSTRIDE];  // normalized hist, bf16
    __shared__ float norm2[MPAD];                     // norms -> scales
    __shared__ int idxS[MPAD];
    __shared__ float lArr[DIM];
    __shared__ float redS[4][4];
    __shared__ float invS[4];

    const int b = blockIdx.x;
    const int tid = threadIdx.x;
    const int wave = tid >> 6;
    const int lane = tid & 63;
    const int quad = lane >> 4;
    const int l16 = lane & 15;

    if (tid < MPAD) {
        idxS[tid] = (tid < HIST) ? batch_history[b * HIST + tid] : 0;
        norm2[tid] = 0.f;
    }
    __syncthreads();

    // acc init with C (latency overlaps the gather below).
    // D-layout: row m = mt*16 + quad*4 + r, col n = (wave*4+i)*16 + l16
    f32x4 acc[13][4];
#pragma unroll
    for (int mt = 0; mt < 13; ++mt)
#pragma unroll
        for (int i = 0; i < 4; ++i)
#pragma unroll
            for (int r = 0; r < 4; ++r) {
                int m = mt * 16 + quad * 4 + r;
                int n = (wave * 4 + i) * 16 + l16;
                acc[mt][i][r] = (m < HIST) ? Cmat[m * DIM + n] : 0.f;
            }

    // ---- stage: gather venue rows -> bf16 LDS, accumulate row norms ----
    for (int it = 0; it < 52; ++it) {
        int c = tid + it * 256;          // 208 rows * 64 float4-chunks
        int m = c >> 6, p = c & 63;
        const float4 g = *(const float4*)(venue_emb + (size_t)idxS[m] * DIM + p * 4);
        atomicAdd(&norm2[m], g.x * g.x + g.y * g.y + g.z * g.z + g.w * g.w);
        union { ushort4 u4; unsigned short h[4]; } pk;
        pk.h[0] = f2bf(g.x); pk.h[1] = f2bf(g.y); pk.h[2] = f2bf(g.z); pk.h[3] = f2bf(g.w);
        *(ushort4*)&histS[m * HSTRIDE + p * 4] = pk.u4;
    }
    __syncthreads();
    if (tid < MPAD) {
        float nn = sqrtf(norm2[tid]);
        norm2[tid] = fminf(1.f, 1.f / fmaxf(nn, EPSF));   // now: max_norm scale s_m
    }
    __syncthreads();
    // ---- apply max_norm scale in place ----
    for (int it = 0; it < 52; ++it) {
        int c = tid + it * 256;
        int m = c >> 6, p = c & 63;
        float s = norm2[m];
        unsigned short* ptr = &histS[m * HSTRIDE + p * 4];
        ushort4 u = *(ushort4*)ptr;
        union { ushort4 u4; unsigned short h[4]; } pk;
        pk.h[0] = f2bf(bf2f(u.x) * s); pk.h[1] = f2bf(bf2f(u.y) * s);
        pk.h[2] = f2bf(bf2f(u.z) * s); pk.h[3] = f2bf(bf2f(u.w) * s);
        *(ushort4*)ptr = pk.u4;
    }
    __syncthreads();

    // ---- MFMA: acc += hist[208x256] @ W1[256x256] (per-wave: 13 m x 4 n) ----
#pragma unroll
    for (int k = 0; k < 8; ++k) {
        bf16x8 Bf[4];
#pragma unroll
        for (int i = 0; i < 4; ++i) {
            int n = (wave * 4 + i) * 16 + l16;
            Bf[i] = *(const bf16x8*)(const void*)(W1t + n * DIM + k * 32 + quad * 8);
        }
#pragma unroll
        for (int mt = 0; mt < 13; ++mt) {
            const bf16x8 Af =
                *(const bf16x8*)(const void*)(&histS[(mt * 16 + l16) * HSTRIDE + k * 32 + quad * 8]);
#pragma unroll
            for (int i = 0; i < 4; ++i)
                acc[mt][i] = __builtin_amdgcn_mfma_f32_16x16x32_bf16(Af, Bf[i], acc[mt][i], 0, 0, 0);
        }
    }

    // ---- tanh + softmax-over-m + weighted sum, all in registers ----
    // h in (-1,1) => exp(h) bounded => no max-subtraction needed.
    const float a_val = a_ptr[0];
    float Ssum[4] = {0.f, 0.f, 0.f, 0.f};
    float Lnum[4] = {0.f, 0.f, 0.f, 0.f};
#pragma unroll
    for (int i = 0; i < 4; ++i) {
        int n = (wave * 4 + i) * 16 + l16;
#pragma unroll
        for (int mt = 0; mt < 13; ++mt)
#pragma unroll
            for (int r = 0; r < 4; ++r) {
                int m = mt * 16 + quad * 4 + r;
                if (m < HIST) {
                    float x = acc[mt][i][r];
                    float e2 = __expf(2.f * x);
                    float th = 1.f - 2.f / (e2 + 1.f);     // tanh(x)
                    float e = __expf(th);
                    Ssum[i] += e;
                    Lnum[i] += e * bf2f(histS[m * HSTRIDE + n]);
                }
            }
    }
#pragma unroll
    for (int i = 0; i < 4; ++i) {
        Ssum[i] += __shfl_xor(Ssum[i], 16); Ssum[i] += __shfl_xor(Ssum[i], 32);
        Lnum[i] += __shfl_xor(Lnum[i], 16); Lnum[i] += __shfl_xor(Lnum[i], 32);
        if (quad == 0) lArr[(wave * 4 + i) * 16 + l16] = Lnum[i] / Ssum[i] + a_val;
    }
    __syncthreads();

    // ---- epilogue: s = u^ + l^ - v^ ; out = ||s|| ----
    const float lt = lArr[tid];
    const float ut = user_emb[(size_t)batch_u[b] * DIM + tid];
    const float vt = venue_emb[(size_t)batch_v[b] * DIM + tid];
    float pu = ut * ut, pv = vt * vt, pl = lt * lt;
#pragma unroll
    for (int off = 32; off > 0; off >>= 1) {
        pu += __shfl_xor(pu, off);
        pv += __shfl_xor(pv, off);
        pl += __shfl_xor(pl, off);
    }
    if (lane == 0) { redS[wave][0] = pu; redS[wave][1] = pv; redS[wave][2] = pl; }
    __syncthreads();
    if (tid == 0) {
        float su = 0.f, sv = 0.f, sl = 0.f;
        for (int w = 0; w < 4; ++w) { su += redS[w][0]; sv += redS[w][1]; sl += redS[w][2]; }
        invS[0] = 1.f / fmaxf(sqrtf(su), EPSF);
        invS[1] = 1.f / fmaxf(sqrtf(sv), EPSF);
        invS[2] = 1.f / fmaxf(sqrtf(sl), EPSF);
    }
    __syncthreads();
    float s = ut * invS[0] + lt * invS[2] - vt * invS[1];
    float s2 = s * s;
#pragma unroll
    for (int off = 32; off > 0; off >>= 1) s2 += __shfl_xor(s2, off);
    if (lane == 0) redS[wave][3] = s2;
    __syncthreads();
    if (tid == 0) out[b] = sqrtf(redS[0][3] + redS[1][3] + redS[2][3] + redS[3][3]);
}

extern "C" void kernel_launch(void* const* d_in, const int* in_sizes, int n_in,
                              void* d_out, int out_size, void* d_ws, size_t ws_size,
                              hipStream_t stream) {
    const int* batch_u = (const int*)d_in[0];
    const int* batch_v = (const int*)d_in[1];
    const int* batch_history = (const int*)d_in[2];
    // d_in[3], d_in[4]: olc inputs, unused by the reference forward
    const float* user_emb = (const float*)d_in[5];
    const float* venue_emb = (const float*)d_in[6];
    const float* W1 = (const float*)d_in[7];
    const float* W2 = (const float*)d_in[8];
    const float* P = (const float*)d_in[9];
    const float* bias = (const float*)d_in[10];
    const float* a = (const float*)d_in[11];
    float* out = (float*)d_out;

    float* C = (float*)d_ws;                                         // 200*256*4 = 204800 B
    unsigned short* W1t = (unsigned short*)((char*)d_ws + HIST * DIM * sizeof(float)); // 128 KiB

    k_w1t<<<16, 256, 0, stream>>>(W1, W1t);
    k_C<<<HIST, 256, 0, stream>>>(P, W2, bias, C);
    k_main<<<BATCH, 256, 0, stream>>>(batch_u, batch_v, batch_history,
                                      user_emb, venue_emb, C, W1t, a, out);
}

// Round 2
// 470.093 us; speedup vs baseline: 1.3861x; 1.3861x over previous
//
#include <hip/hip_runtime.h>

#define DIM 256
#define HIST 200
#define MPAD 208          // 13 m-tiles of 16
#define BATCH 2048
#define HSTRIDE 264       // hist row stride in bf16 elems (+8 -> 16B shift)
#define EPSF 1e-12f

typedef __bf16 bf16x8 __attribute__((ext_vector_type(8)));
typedef float f32x4 __attribute__((ext_vector_type(4)));

__device__ __forceinline__ unsigned short f2bf(float f) {
    union { float f; unsigned u; } v; v.f = f;
    unsigned r = (v.u + 0x7fffu + ((v.u >> 16) & 1u)) >> 16;
    return (unsigned short)r;
}
__device__ __forceinline__ float bf2f(unsigned short u) {
    union { unsigned u; float f; } v; v.u = ((unsigned)u) << 16;
    return v.f;
}

// ---------- prep 0: per-venue max_norm scale: min(1, 1/max(||row||,eps)) ----------
__global__ __launch_bounds__(256) void k_vscale(const float* __restrict__ venue,
                                                float* __restrict__ sInv, int nrows) {
    const int row = blockIdx.x * 4 + (threadIdx.x >> 6);
    if (row >= nrows) return;
    const int lane = threadIdx.x & 63;
    const float4 g = *(const float4*)(venue + (size_t)row * DIM + lane * 4);
    float ss = g.x * g.x + g.y * g.y + g.z * g.z + g.w * g.w;
#pragma unroll
    for (int off = 32; off > 0; off >>= 1) ss += __shfl_xor(ss, off);
    if (lane == 0) sInv[row] = fminf(1.f, 1.f / fmaxf(sqrtf(ss), EPSF));
}

// ---------- prep 1: W1t[n][k] = bf16(W1[k][n]) ----------
__global__ __launch_bounds__(256) void k_w1t(const float* __restrict__ W1,
                                             unsigned short* __restrict__ W1t) {
    __shared__ float tile[64][65];
    const int bi = blockIdx.x >> 2;   // k-block
    const int bj = blockIdx.x & 3;    // n-block
    const int tid = threadIdx.x;
#pragma unroll
    for (int it = 0; it < 16; ++it) {
        int idx = tid + it * 256;
        int r = idx >> 6, c = idx & 63;
        tile[r][c] = W1[(bi * 64 + r) * DIM + bj * 64 + c];
    }
    __syncthreads();
#pragma unroll
    for (int it = 0; it < 16; ++it) {
        int idx = tid + it * 256;
        int c = idx >> 6, r = idx & 63;
        W1t[(bj * 64 + c) * DIM + bi * 64 + r] = f2bf(tile[r][c]);
    }
}

// ---------- prep 2: Ct[n][m] = (P @ W2 + bias)[m][n]  (fp32, [DIM][MPAD]) ----------
__global__ __launch_bounds__(256) void k_Ct(const float* __restrict__ P,
                                            const float* __restrict__ W2,
                                            const float* __restrict__ bias,
                                            float* __restrict__ Ct) {
    __shared__ float Prow[DIM];
    const int h = blockIdx.x, e = threadIdx.x;
    Prow[e] = P[h * DIM + e];
    __syncthreads();
    float acc = bias[h * DIM + e];
#pragma unroll 8
    for (int d = 0; d < DIM; ++d) acc += Prow[d] * W2[d * DIM + e];
    Ct[e * MPAD + h] = acc;
}

// ---------- main: one block per batch element ----------
__global__ __launch_bounds__(256, 1) void k_main(
    const int* __restrict__ batch_u, const int* __restrict__ batch_v,
    const int* __restrict__ batch_history,
    const float* __restrict__ user_emb, const float* __restrict__ venue_emb,
    const float* __restrict__ Ct, const unsigned short* __restrict__ W1t,
    const float* __restrict__ sInv,
    const float* __restrict__ a_ptr, float* __restrict__ out) {

    __shared__ unsigned short histS[MPAD * HSTRIDE];  // normalized hist, bf16
    __shared__ float scaleS[MPAD];
    __shared__ int idxS[MPAD];
    __shared__ float lArr[DIM];
    __shared__ float redS[4][4];
    __shared__ float invS[4];

    const int b = blockIdx.x;
    const int tid = threadIdx.x;
    const int wave = tid >> 6;
    const int lane = tid & 63;
    const int quad = lane >> 4;
    const int l16 = lane & 15;
    // permuted column ownership: lane l16, tile i -> n = wave*64 + l16*4 + i
    const int ncol0 = wave * 64 + l16 * 4;

    if (tid < MPAD) {
        int m = (tid < HIST) ? tid : 0;
        int ix = batch_history[b * HIST + m];
        idxS[tid] = ix;
        scaleS[tid] = sInv[ix];
    }
    __syncthreads();

    // acc init with C in transposed layout (vector loads); latency overlaps gather.
    // D-layout: row m = mt*16 + quad*4 + r, col n = ncol0 + i
    f32x4 acc[13][4];
#pragma unroll
    for (int mt = 0; mt < 13; ++mt)
#pragma unroll
        for (int i = 0; i < 4; ++i)
            acc[mt][i] = *(const f32x4*)(Ct + (ncol0 + i) * MPAD + mt * 16 + quad * 4);

    // ---- gather: wave handles rows [wave*52, wave*52+52); 8-deep pipeline ----
    const int r0 = wave * 52;
    float4 buf[8];
#pragma unroll
    for (int j = 0; j < 8; ++j)
        buf[j] = *(const float4*)(venue_emb + (size_t)idxS[r0 + j] * DIM + lane * 4);
#pragma unroll
    for (int j = 0; j < 52; ++j) {
        float4 g = buf[j % 8];
        if (j + 8 < 52)
            buf[j % 8] = *(const float4*)(venue_emb + (size_t)idxS[r0 + j + 8] * DIM + lane * 4);
        float s = scaleS[r0 + j];
        ushort4 pk = { f2bf(g.x * s), f2bf(g.y * s), f2bf(g.z * s), f2bf(g.w * s) };
        *(ushort4*)&histS[(r0 + j) * HSTRIDE + lane * 4] = pk;
    }
    __syncthreads();

    // prefetch u/v rows early; latency hides under MFMA + exp phases
    const float ut = user_emb[(size_t)batch_u[b] * DIM + tid];
    const float vt = venue_emb[(size_t)batch_v[b] * DIM + tid];

    // ---- MFMA: acc += hist[208x256] @ W1[256x256] (per-wave: 13 m x 4 n) ----
#pragma unroll
    for (int k = 0; k < 8; ++k) {
        bf16x8 Bf[4];
#pragma unroll
        for (int i = 0; i < 4; ++i) {
            int n = ncol0 + i;
            Bf[i] = *(const bf16x8*)(const void*)(W1t + n * DIM + k * 32 + quad * 8);
        }
#pragma unroll
        for (int mt = 0; mt < 13; ++mt) {
            const bf16x8 Af =
                *(const bf16x8*)(const void*)(&histS[(mt * 16 + l16) * HSTRIDE + k * 32 + quad * 8]);
#pragma unroll
            for (int i = 0; i < 4; ++i)
                acc[mt][i] = __builtin_amdgcn_mfma_f32_16x16x32_bf16(Af, Bf[i], acc[mt][i], 0, 0, 0);
        }
    }

    // ---- tanh + softmax-over-m + weighted sum ----
    // h in (-1,1) => exp(h) bounded => no max-subtraction needed.
    const float a_val = a_ptr[0];
    float Ssum[4] = {0.f, 0.f, 0.f, 0.f};
    float Lnum[4] = {0.f, 0.f, 0.f, 0.f};
#pragma unroll
    for (int mt = 0; mt < 13; ++mt)
#pragma unroll
        for (int r = 0; r < 4; ++r) {
            int m = mt * 16 + quad * 4 + r;
            if (m < HIST) {
                // 4 consecutive bf16 columns (ncol0..+3) in one 8B read
                ushort4 hv = *(const ushort4*)&histS[m * HSTRIDE + ncol0];
                float hw[4] = { bf2f(hv.x), bf2f(hv.y), bf2f(hv.z), bf2f(hv.w) };
#pragma unroll
                for (int i = 0; i < 4; ++i) {
                    float x = acc[mt][i][r];
                    float e2 = __expf(2.f * x);
                    float th = 1.f - 2.f / (e2 + 1.f);     // tanh(x)
                    float e = __expf(th);
                    Ssum[i] += e;
                    Lnum[i] += e * hw[i];
                }
            }
        }
#pragma unroll
    for (int i = 0; i < 4; ++i) {
        Ssum[i] += __shfl_xor(Ssum[i], 16); Ssum[i] += __shfl_xor(Ssum[i], 32);
        Lnum[i] += __shfl_xor(Lnum[i], 16); Lnum[i] += __shfl_xor(Lnum[i], 32);
        if (quad == 0) lArr[ncol0 + i] = Lnum[i] / Ssum[i] + a_val;
    }
    __syncthreads();

    // ---- epilogue: s = u^ + l^ - v^ ; out = ||s|| ----
    const float lt = lArr[tid];
    float pu = ut * ut, pv = vt * vt, pl = lt * lt;
#pragma unroll
    for (int off = 32; off > 0; off >>= 1) {
        pu += __shfl_xor(pu, off);
        pv += __shfl_xor(pv, off);
        pl += __shfl_xor(pl, off);
    }
    if (lane == 0) { redS[wave][0] = pu; redS[wave][1] = pv; redS[wave][2] = pl; }
    __syncthreads();
    if (tid == 0) {
        float su = 0.f, sv = 0.f, sl = 0.f;
        for (int w = 0; w < 4; ++w) { su += redS[w][0]; sv += redS[w][1]; sl += redS[w][2]; }
        invS[0] = 1.f / fmaxf(sqrtf(su), EPSF);
        invS[1] = 1.f / fmaxf(sqrtf(sv), EPSF);
        invS[2] = 1.f / fmaxf(sqrtf(sl), EPSF);
    }
    __syncthreads();
    float s = ut * invS[0] + lt * invS[2] - vt * invS[1];
    float s2 = s * s;
#pragma unroll
    for (int off = 32; off > 0; off >>= 1) s2 += __shfl_xor(s2, off);
    if (lane == 0) redS[wave][3] = s2;
    __syncthreads();
    if (tid == 0) out[b] = sqrtf(redS[0][3] + redS[1][3] + redS[2][3] + redS[3][3]);
}

extern "C" void kernel_launch(void* const* d_in, const int* in_sizes, int n_in,
                              void* d_out, int out_size, void* d_ws, size_t ws_size,
                              hipStream_t stream) {
    const int* batch_u = (const int*)d_in[0];
    const int* batch_v = (const int*)d_in[1];
    const int* batch_history = (const int*)d_in[2];
    // d_in[3], d_in[4]: olc inputs, unused by the reference forward
    const float* user_emb = (const float*)d_in[5];
    const float* venue_emb = (const float*)d_in[6];
    const float* W1 = (const float*)d_in[7];
    const float* W2 = (const float*)d_in[8];
    const float* P = (const float*)d_in[9];
    const float* bias = (const float*)d_in[10];
    const float* a = (const float*)d_in[11];
    float* out = (float*)d_out;

    const int nV = in_sizes[6] / DIM;

    // ws layout (all 256B-aligned): Ct [256][208] f32 | W1t [256][256] bf16 | sInv [nV] f32
    float* Ct = (float*)d_ws;                                           // 212992 B
    unsigned short* W1t = (unsigned short*)((char*)d_ws + 212992);      // 131072 B
    float* sInv = (float*)((char*)d_ws + 212992 + 131072);              // nV*4 B

    k_vscale<<<(nV + 3) / 4, 256, 0, stream>>>(venue_emb, sInv, nV);
    k_w1t<<<16, 256, 0, stream>>>(W1, W1t);
    k_Ct<<<HIST, 256, 0, stream>>>(P, W2, bias, Ct);
    k_main<<<BATCH, 256, 0, stream>>>(batch_u, batch_v, batch_history,
                                      user_emb, venue_emb, Ct, W1t, sInv, a, out);
}

// Round 3
// 413.080 us; speedup vs baseline: 1.5774x; 1.1380x over previous
//
#include <hip/hip_runtime.h>

#define DIM 256
#define HIST 200
#define MPAD 208          // 13 m-tiles of 16
#define BATCH 2048
#define HSTRIDE 264       // hist row stride in bf16 elems (+8 -> 16B shift)
#define EPSF 1e-12f

typedef __bf16 bf16x8 __attribute__((ext_vector_type(8)));
typedef float f32x4 __attribute__((ext_vector_type(4)));

__device__ __forceinline__ unsigned short f2bf(float f) {
    union { float f; unsigned u; } v; v.f = f;
    unsigned r = (v.u + 0x7fffu + ((v.u >> 16) & 1u)) >> 16;
    return (unsigned short)r;
}
__device__ __forceinline__ float bf2f(unsigned short u) {
    union { unsigned u; float f; } v; v.u = ((unsigned)u) << 16;
    return v.f;
}

// ---------- fused prep ----------
// bid [0,16):      W1t2[g*2048 + n*8 + j] = bf16(W1[(g*8+j)*DIM + n]), g=k-group of 8
// bid [16,224):    Ct2[((m>>4)*4 + ((m>>2)&3))*1024 + n*4 + (m&3)] = (P@W2+bias)[m][n], 0 for m>=200
// bid [224,...):   sInv[row] = min(1, 1/max(||venue[row]||, eps)), 4 rows/block
__global__ __launch_bounds__(256) void k_prep(
    const float* __restrict__ W1, const float* __restrict__ P,
    const float* __restrict__ W2, const float* __restrict__ bias,
    const float* __restrict__ venue,
    unsigned short* __restrict__ W1t2, float* __restrict__ Ct2,
    float* __restrict__ sInv, int nV) {
    const int bid = blockIdx.x, tid = threadIdx.x;
    if (bid < 16) {
#pragma unroll
        for (int it = 0; it < 16; ++it) {
            int idx = bid * 4096 + it * 256 + tid;      // [0, 65536)
            int g = idx >> 11, rem = idx & 2047;
            int n = rem >> 3, j = rem & 7;
            W1t2[idx] = f2bf(W1[(g * 8 + j) * DIM + n]);
        }
    } else if (bid < 224) {
        const int h = bid - 16;                          // m index [0,208)
        __shared__ float Prow[DIM];
        const int e = tid;
        float acc = 0.f;
        if (h < HIST) {
            Prow[e] = P[h * DIM + e];
            __syncthreads();
            acc = bias[h * DIM + e];
#pragma unroll 8
            for (int d = 0; d < DIM; ++d) acc += Prow[d] * W2[d * DIM + e];
        }
        Ct2[((h >> 4) * 4 + ((h >> 2) & 3)) * 1024 + e * 4 + (h & 3)] = acc;
    } else {
        const int row = (bid - 224) * 4 + (tid >> 6);
        if (row >= nV) return;
        const int lane = tid & 63;
        const float4 g = *(const float4*)(venue + (size_t)row * DIM + lane * 4);
        float ss = g.x * g.x + g.y * g.y + g.z * g.z + g.w * g.w;
#pragma unroll
        for (int off = 32; off > 0; off >>= 1) ss += __shfl_xor(ss, off);
        if (lane == 0) sInv[row] = fminf(1.f, 1.f / fmaxf(sqrtf(ss), EPSF));
    }
}

// ---------- main: one 1024-thread block (16 waves, 4/SIMD) per batch element ----------
__global__ __launch_bounds__(1024, 4) void k_main(
    const int* __restrict__ batch_u, const int* __restrict__ batch_v,
    const int* __restrict__ batch_history,
    const float* __restrict__ user_emb, const float* __restrict__ venue_emb,
    const float* __restrict__ Ct2, const unsigned short* __restrict__ W1t2,
    const float* __restrict__ sInv,
    const float* __restrict__ a_ptr, float* __restrict__ out) {

    __shared__ unsigned short histS[MPAD * HSTRIDE];  // normalized hist, bf16 (~107 KB)
    __shared__ float scaleS[MPAD];
    __shared__ int idxS[MPAD];
    __shared__ float lArr[DIM];
    __shared__ float redS[4][4];
    __shared__ float invS[3];

    const int b = blockIdx.x;
    const int tid = threadIdx.x;
    const int wave = tid >> 6;        // 0..15, owns n-tile [wave*16, wave*16+16)
    const int lane = tid & 63;
    const int quad = lane >> 4;
    const int l16 = lane & 15;
    const int n = wave * 16 + l16;    // this lane's output column

    if (tid < MPAD) {
        int m = (tid < HIST) ? tid : 0;
        int ix = batch_history[b * HIST + m];
        idxS[tid] = ix;
        scaleS[tid] = sInv[ix];
    }
    __syncthreads();

    // ---- gather: wave handles rows [wave*13, wave*13+13), all loads in flight ----
    const int r0 = wave * 13;
    float4 buf[13];
#pragma unroll
    for (int j = 0; j < 13; ++j)
        buf[j] = *(const float4*)(venue_emb + (size_t)idxS[r0 + j] * DIM + lane * 4);
#pragma unroll
    for (int j = 0; j < 13; ++j) {
        float s = scaleS[r0 + j];
        ushort4 pk = { f2bf(buf[j].x * s), f2bf(buf[j].y * s),
                       f2bf(buf[j].z * s), f2bf(buf[j].w * s) };
        *(ushort4*)&histS[(r0 + j) * HSTRIDE + lane * 4] = pk;
    }

    // acc init (coalesced: consecutive l16 -> consecutive float4)
    // D-layout: row m = mt*16 + quad*4 + r, col = n
    f32x4 acc[13];
#pragma unroll
    for (int mt = 0; mt < 13; ++mt)
        acc[mt] = *(const f32x4*)(Ct2 + (mt * 4 + quad) * 1024 + n * 4);

    // prefetch u/v rows (epilogue-only); latency hides under MFMA + exp
    float ut = 0.f, vt = 0.f;
    if (tid < DIM) {
        ut = user_emb[(size_t)batch_u[b] * DIM + tid];
        vt = venue_emb[(size_t)batch_v[b] * DIM + tid];
    }
    __syncthreads();

    // ---- MFMA: acc += hist[208x256] @ W1[256x256]; per wave: 13 m-tiles x 1 n-tile ----
#pragma unroll
    for (int k = 0; k < 8; ++k) {
        // B-frag: lane-contiguous 16B (W1t2[kgroup][n][8])
        const bf16x8 Bf = *(const bf16x8*)(const void*)(W1t2 + (k * 4 + quad) * 2048 + n * 8);
#pragma unroll
        for (int mt = 0; mt < 13; ++mt) {
            const bf16x8 Af =
                *(const bf16x8*)(const void*)(&histS[(mt * 16 + l16) * HSTRIDE + k * 32 + quad * 8]);
            acc[mt] = __builtin_amdgcn_mfma_f32_16x16x32_bf16(Af, Bf, acc[mt], 0, 0, 0);
        }
    }

    // ---- tanh + softmax-over-m + weighted sum ----
    // h in (-1,1) => exp bounded => no max-subtraction needed.
    const float a_val = a_ptr[0];
    float Ssum = 0.f, Lnum = 0.f;
#pragma unroll
    for (int mt = 0; mt < 13; ++mt)
#pragma unroll
        for (int r = 0; r < 4; ++r) {
            int m = mt * 16 + quad * 4 + r;
            if (m < HIST) {
                float x = acc[mt][r];
                float e2 = __expf(2.f * x);
                float th = 1.f - 2.f / (e2 + 1.f);     // tanh(x)
                float e = __expf(th);
                Ssum += e;
                Lnum += e * bf2f(histS[m * HSTRIDE + n]);
            }
        }
    Ssum += __shfl_xor(Ssum, 16); Ssum += __shfl_xor(Ssum, 32);
    Lnum += __shfl_xor(Lnum, 16); Lnum += __shfl_xor(Lnum, 32);
    if (quad == 0) lArr[n] = Lnum / Ssum + a_val;
    __syncthreads();

    // ---- epilogue: s = u^ + l^ - v^ ; out = ||s|| (waves 4..15 contribute zeros) ----
    const float lt = (tid < DIM) ? lArr[tid] : 0.f;
    float pu = ut * ut, pv = vt * vt, pl = lt * lt;
#pragma unroll
    for (int off = 32; off > 0; off >>= 1) {
        pu += __shfl_xor(pu, off);
        pv += __shfl_xor(pv, off);
        pl += __shfl_xor(pl, off);
    }
    if (lane == 0 && wave < 4) { redS[wave][0] = pu; redS[wave][1] = pv; redS[wave][2] = pl; }
    __syncthreads();
    if (tid == 0) {
        float su = 0.f, sv = 0.f, sl = 0.f;
        for (int w = 0; w < 4; ++w) { su += redS[w][0]; sv += redS[w][1]; sl += redS[w][2]; }
        invS[0] = 1.f / fmaxf(sqrtf(su), EPSF);
        invS[1] = 1.f / fmaxf(sqrtf(sv), EPSF);
        invS[2] = 1.f / fmaxf(sqrtf(sl), EPSF);
    }
    __syncthreads();
    float s = ut * invS[0] + lt * invS[2] - vt * invS[1];
    float s2 = s * s;
#pragma unroll
    for (int off = 32; off > 0; off >>= 1) s2 += __shfl_xor(s2, off);
    if (lane == 0 && wave < 4) redS[wave][3] = s2;
    __syncthreads();
    if (tid == 0) out[b] = sqrtf(redS[0][3] + redS[1][3] + redS[2][3] + redS[3][3]);
}

extern "C" void kernel_launch(void* const* d_in, const int* in_sizes, int n_in,
                              void* d_out, int out_size, void* d_ws, size_t ws_size,
                              hipStream_t stream) {
    const int* batch_u = (const int*)d_in[0];
    const int* batch_v = (const int*)d_in[1];
    const int* batch_history = (const int*)d_in[2];
    // d_in[3], d_in[4]: olc inputs, unused by the reference forward
    const float* user_emb = (const float*)d_in[5];
    const float* venue_emb = (const float*)d_in[6];
    const float* W1 = (const float*)d_in[7];
    const float* W2 = (const float*)d_in[8];
    const float* P = (const float*)d_in[9];
    const float* bias = (const float*)d_in[10];
    const float* a = (const float*)d_in[11];
    float* out = (float*)d_out;

    const int nV = in_sizes[6] / DIM;

    // ws layout: Ct2 [13*4*256*4] f32 (212992 B) | W1t2 [32*256*8] bf16 (131072 B) | sInv [nV] f32
    float* Ct2 = (float*)d_ws;
    unsigned short* W1t2 = (unsigned short*)((char*)d_ws + 212992);
    float* sInv = (float*)((char*)d_ws + 212992 + 131072);

    k_prep<<<224 + (nV + 3) / 4, 256, 0, stream>>>(W1, P, W2, bias, venue_emb,
                                                   W1t2, Ct2, sInv, nV);
    k_main<<<BATCH, 1024, 0, stream>>>(batch_u, batch_v, batch_history,
                                       user_emb, venue_emb, Ct2, W1t2, sInv, a, out);
}